// Round 3
// baseline (103.166 us; speedup 1.0000x reference)
//
#include <hip/hip_runtime.h>

// Chamfer distance: B=8, N=M=8192, D=3, fp32, via bf16 split-precision MFMA.
// R10: R9 post-mortem: m-split+DMA+min3 gained nothing (45.4 -> 48.3us).
//   (1) Barrier-locked dbuf: 17x per-block vmcnt(0)+s_barrier convoys ->
//       occupancy 22% not 50%. (2) VALUBusy 19.2us vs 7us floor: MFMA
//       results went to AGPRs (VGPR=72 can't hold best32+czero16+d32),
//       v_min3 can't read 2 AGPRs -> unfused mins/moves.
//   Fix both structurally:
//   (a) NO LDS staging, NO main-loop barriers. bpack is 4MiB; XCD = dirb%8
//       (linear id = dirb + 16*y) so each XCD reads only its 2 dirb slices
//       = 2MiB, L2-resident. Each wave streams 128 coalesced 1KB B-frag
//       loads from L2 directly; waves fully independent; 4 waves/SIMD TLP
//       hides L2 latency. Critical pipe becomes per-XCD L2 BW (~14us).
//   (b) inline-asm MFMA with "=&v" -> d0/d1 in arch VGPRs -> min3 fuses.
//       s_nop 7+3 in-asm + sched_barrier(VALU blocked) cover the 18
//       wait-state MFMA->VALU-read hazard. Per-p fold groups keep only
//       2 d-vectors live -> ~120 VGPR -> 4 waves/SIMD at launch_bounds 4.

#define B_DIM 8
#define N_DIM 8192
#define MT    (N_DIM / 32)      // 256 m-tiles per (dir,b)
#define BLOCK 256
#define PPW   2                 // n-tiles per wave

typedef short  bf16x8 __attribute__((ext_vector_type(8)));
typedef float  f32x16 __attribute__((ext_vector_type(16)));

__device__ __forceinline__ unsigned short bf16_rne(float f) {
    unsigned int u = __float_as_uint(f);
    u += 0x7fffu + ((u >> 16) & 1u);
    return (unsigned short)(u >> 16);
}
__device__ __forceinline__ float bf16f(unsigned short h) {
    return __uint_as_float(((unsigned int)h) << 16);
}

// Pack B-fragments for both directions. Layout: 16-byte frags indexed
// [dirb][mtile][half][m32] so a wave's 64 lanes read 1024 contiguous bytes.
__global__ __launch_bounds__(256) void chamfer_prep(
    const float* __restrict__ pred, const float* __restrict__ gt,
    unsigned short* __restrict__ bpack, float* __restrict__ out)
{
    const int i   = blockIdx.x * 256 + threadIdx.x;  // 0 .. 2*B*N-1
    if (i == 0) out[0] = 0.0f;
    const int dir = i >> 16;
    const int bm  = i & 0xFFFF;                      // b*N + m
    const float* dst = dir ? pred : gt;
    const float x = dst[3*bm+0], y = dst[3*bm+1], z = dst[3*bm+2];
    const unsigned short hx = bf16_rne(x), hy = bf16_rne(y), hz = bf16_rne(z);
    const unsigned short lx = bf16_rne(x - bf16f(hx));
    const unsigned short ly = bf16_rne(y - bf16f(hy));
    const unsigned short lz = bf16_rne(z - bf16f(hz));
    const float gn = x*x + y*y + z*z;
    const unsigned short gnh = bf16_rne(gn), gnl = bf16_rne(gn - bf16f(gnh));
    const unsigned short one = 0x3F80;

    const int b  = bm >> 13, m = bm & (N_DIM - 1);
    const int mt = m >> 5,   c = m & 31;
    const int dirb = (dir << 3) | b;
    unsigned short* p0 = bpack + ((size_t)(dirb * MT + mt) * 64 + c) * 8;
    unsigned short* p1 = p0 + 32 * 8;
    // half0 = k0..7 : gh(xyz) gl(xyz) gh(x,y) ; half1 = k8..15 : gh(z) 1 1 gnh gnl 0 0 0
    bf16x8 h0 = {(short)hx,(short)hy,(short)hz,(short)lx,(short)ly,(short)lz,(short)hx,(short)hy};
    bf16x8 h1 = {(short)hz,(short)one,(short)one,(short)gnh,(short)gnl,0,0,0};
    *(bf16x8*)p0 = h0;
    *(bf16x8*)p1 = h1;
}

__global__ __launch_bounds__(BLOCK, 4) void chamfer_partial(
    const float* __restrict__ pred, const float* __restrict__ gt,
    const bf16x8* __restrict__ bpack, float* __restrict__ out)
{
    __shared__ float cbuf[PPW * 16 * 128];  // 16 KB combine buffer (epilogue only)
    __shared__ float wsum[2];
    const int dirb = blockIdx.x;            // low grid bits -> XCD = dirb%8
    const int dir  = dirb >> 3, b = dirb & 7;
    const int w    = threadIdx.x >> 6, lane = threadIdx.x & 63;
    const int halfk = lane >> 5,  col = lane & 31;
    const int nsub = w & 1;                 // which n-tile pair
    const int mh   = w >> 1;                // m-half: 0 -> tiles 0..127, 1 -> 128..255

    const float* src  = dir ? gt : pred;
    const float* srcb = src + (size_t)b * N_DIM * 3;

    // A fragments for this wave's PPW n-tiles (row = col, k-half = halfk).
    bf16x8 afrag[PPW];
    #pragma unroll
    for (int p = 0; p < PPW; ++p) {
        const int ntile = blockIdx.y * 4 + nsub * 2 + p;
        const int n = ntile * 32 + col;
        const float x = srcb[3*n+0], y = srcb[3*n+1], z = srcb[3*n+2];
        const float ax = -2.f*x, ay = -2.f*y, az = -2.f*z;
        const unsigned short ahx = bf16_rne(ax), ahy = bf16_rne(ay), ahz = bf16_rne(az);
        const unsigned short alx = bf16_rne(ax - bf16f(ahx));
        const unsigned short aly = bf16_rne(ay - bf16f(ahy));
        const unsigned short alz = bf16_rne(az - bf16f(ahz));
        const float pn = x*x + y*y + z*z;
        const unsigned short pnh = bf16_rne(pn), pnl = bf16_rne(pn - bf16f(pnh));
        const unsigned short one = 0x3F80;
        bf16x8 a0 = {(short)ahx,(short)ahy,(short)ahz,(short)ahx,(short)ahy,(short)ahz,(short)alx,(short)aly};
        bf16x8 a1 = {(short)alz,(short)pnh,(short)pnl,(short)one,(short)one,0,0,0};
        afrag[p] = (halfk == 0) ? a0 : a1;
    }

    const f32x16 czero = {0.f,0.f,0.f,0.f,0.f,0.f,0.f,0.f,
                          0.f,0.f,0.f,0.f,0.f,0.f,0.f,0.f};
    float best[PPW][16];
    #pragma unroll
    for (int p = 0; p < PPW; ++p)
        #pragma unroll
        for (int r = 0; r < 16; ++r) best[p][r] = 1e30f;

    // This wave's B-fragment stream: 128 m-tiles, 1 KB (wave) per tile,
    // coalesced dwordx4 per lane, L2-resident.
    const bf16x8* bw = bpack + (size_t)dirb * (MT * 64) + (size_t)(mh * 128) * 64 + lane;

    for (int t = 0; t < 64; ++t) {
        const bf16x8 c0 = bw[0];     // m-tile 2t
        const bf16x8 c1 = bw[64];    // m-tile 2t+1
        bw += 128;
        // group p=0: two MFMAs (VGPR-forced), nops cover 18 wait states
        f32x16 d0, d1;
        asm volatile(
            "v_mfma_f32_32x32x16_bf16 %0, %2, %3, %5\n\t"
            "v_mfma_f32_32x32x16_bf16 %1, %2, %4, %5\n\t"
            "s_nop 7\n\t"
            "s_nop 3"
            : "=&v"(d0), "=&v"(d1)
            : "v"(afrag[0]), "v"(c0), "v"(c1), "v"(czero));
        __builtin_amdgcn_sched_barrier(0x34);   // VALU may not cross; VMEM/SALU may
        #pragma unroll
        for (int r = 0; r < 16; ++r)
            best[0][r] = fminf(fminf(best[0][r], d0[r]), d1[r]);  // v_min3_f32
        // group p=1
        f32x16 d2, d3;
        asm volatile(
            "v_mfma_f32_32x32x16_bf16 %0, %2, %3, %5\n\t"
            "v_mfma_f32_32x32x16_bf16 %1, %2, %4, %5\n\t"
            "s_nop 7\n\t"
            "s_nop 3"
            : "=&v"(d2), "=&v"(d3)
            : "v"(afrag[1]), "v"(c0), "v"(c1), "v"(czero));
        __builtin_amdgcn_sched_barrier(0x34);
        #pragma unroll
        for (int r = 0; r < 16; ++r)
            best[1][r] = fminf(fminf(best[1][r], d2[r]), d3[r]);
    }

    // Combine the two m-halves: waves 2,3 export best[] through LDS,
    // waves 0,1 min-combine. Lanes contiguous -> conflict-free.
    if (mh == 1) {
        #pragma unroll
        for (int p = 0; p < PPW; ++p)
            #pragma unroll
            for (int r = 0; r < 16; ++r)
                cbuf[(p * 16 + r) * 128 + nsub * 64 + lane] = best[p][r];
    }
    __syncthreads();
    if (mh == 0) {
        float bsum = 0.f;
        #pragma unroll
        for (int p = 0; p < PPW; ++p) {
            float s = 0.f;
            #pragma unroll
            for (int r = 0; r < 16; ++r) {
                float v = fminf(best[p][r], cbuf[(p * 16 + r) * 128 + nsub * 64 + lane]);
                v = fminf(v, __shfl_xor(v, 1,  64));
                v = fminf(v, __shfl_xor(v, 2,  64));
                v = fminf(v, __shfl_xor(v, 4,  64));
                v = fminf(v, __shfl_xor(v, 8,  64));
                v = fminf(v, __shfl_xor(v, 16, 64));
                s += v;                       // 16 final row-mins of this k-half
            }
            bsum += s + __shfl_xor(s, 32, 64);  // add other k-half's 16 rows
        }
        if (lane == 0) wsum[nsub] = bsum;
    }
    __syncthreads();
    if (threadIdx.x == 0) {
        const float scale = 100.0f * 0.5f / ((float)B_DIM * (float)N_DIM);
        atomicAdd(out, (wsum[0] + wsum[1]) * scale);
    }
}

extern "C" void kernel_launch(void* const* d_in, const int* in_sizes, int n_in,
                              void* d_out, int out_size, void* d_ws, size_t ws_size,
                              hipStream_t stream) {
    const float* pred = (const float*)d_in[0];
    const float* gt   = (const float*)d_in[1];
    float* out = (float*)d_out;
    unsigned short* bpack = (unsigned short*)d_ws;   // 4 MiB

    chamfer_prep<<<(2 * B_DIM * N_DIM) / 256, 256, 0, stream>>>(pred, gt, bpack, out);

    // dirb x n-chunks(128 pts) = 16 x 64 = 1024 blocks, 4 indep waves each
    dim3 grid(16, N_DIM / 128);
    chamfer_partial<<<grid, BLOCK, 0, stream>>>(pred, gt, (const bf16x8*)bpack, out);
}

// Round 5
// 102.393 us; speedup vs baseline: 1.0075x; 1.0075x over previous
//
#include <hip/hip_runtime.h>

// Chamfer distance: B=8, N=M=8192, D=3, fp32, via bf16 split-precision MFMA.
// R12: R11 failed correctness (absmax 12.8): builtin-MFMA results consumed
//   by inline-asm v_min3 -> compiler's hazard recognizer does NOT guard
//   MFMA->inline-asm-VALU reads -> min3 executed in the MFMA's 18-wait-
//   state shadow. Proven-correct pattern is the inverse (R10): MFMA in asm
//   with in-asm s_nop 7/3, fold in C++ fminf.
//   R10's real defect was register pressure: czero asm input (16) pushed
//   demand to ~130 > 128 @ 4 waves/EU -> best[] spilled to AGPR -> every
//   min became accvgpr_read/min/accvgpr_write (VALU 18us vs 6.8 floor).
//   Fix: MFMA src2 = inline constant 0 (VOP3P-MAI src fields accept inline
//   consts) -> czero deleted, demand ~105 <= 128 -> best stays arch-VGPR,
//   fold fuses to v_min3 with VGPR operands. No prefetch regs (TLP covers
//   L2 latency at 4 waves/SIMD, per R10's memory-side behavior).
//   Structure (from R10): no LDS staging, no main-loop barriers; XCD =
//   dirb%8 so each XCD streams only its 2 dirb slices (512KB unique,
//   L2-resident). Floors: L2 ~15us, VALU ~6.8us, MFMA 3.4us.

#define B_DIM 8
#define N_DIM 8192
#define MT    (N_DIM / 32)      // 256 m-tiles per (dir,b)
#define BLOCK 256
#define PPW   2                 // n-tiles per wave

typedef short  bf16x8 __attribute__((ext_vector_type(8)));
typedef float  f32x16 __attribute__((ext_vector_type(16)));

__device__ __forceinline__ unsigned short bf16_rne(float f) {
    unsigned int u = __float_as_uint(f);
    u += 0x7fffu + ((u >> 16) & 1u);
    return (unsigned short)(u >> 16);
}
__device__ __forceinline__ float bf16f(unsigned short h) {
    return __uint_as_float(((unsigned int)h) << 16);
}

// Pack B-fragments for both directions. Layout: 16-byte frags indexed
// [dirb][mtile][half][m32] so a wave's 64 lanes read 1024 contiguous bytes.
__global__ __launch_bounds__(256) void chamfer_prep(
    const float* __restrict__ pred, const float* __restrict__ gt,
    unsigned short* __restrict__ bpack, float* __restrict__ out)
{
    const int i   = blockIdx.x * 256 + threadIdx.x;  // 0 .. 2*B*N-1
    if (i == 0) out[0] = 0.0f;
    const int dir = i >> 16;
    const int bm  = i & 0xFFFF;                      // b*N + m
    const float* dst = dir ? pred : gt;
    const float x = dst[3*bm+0], y = dst[3*bm+1], z = dst[3*bm+2];
    const unsigned short hx = bf16_rne(x), hy = bf16_rne(y), hz = bf16_rne(z);
    const unsigned short lx = bf16_rne(x - bf16f(hx));
    const unsigned short ly = bf16_rne(y - bf16f(hy));
    const unsigned short lz = bf16_rne(z - bf16f(hz));
    const float gn = x*x + y*y + z*z;
    const unsigned short gnh = bf16_rne(gn), gnl = bf16_rne(gn - bf16f(gnh));
    const unsigned short one = 0x3F80;

    const int b  = bm >> 13, m = bm & (N_DIM - 1);
    const int mt = m >> 5,   c = m & 31;
    const int dirb = (dir << 3) | b;
    unsigned short* p0 = bpack + ((size_t)(dirb * MT + mt) * 64 + c) * 8;
    unsigned short* p1 = p0 + 32 * 8;
    // half0 = k0..7 : gh(xyz) gl(xyz) gh(x,y) ; half1 = k8..15 : gh(z) 1 1 gnh gnl 0 0 0
    bf16x8 h0 = {(short)hx,(short)hy,(short)hz,(short)lx,(short)ly,(short)lz,(short)hx,(short)hy};
    bf16x8 h1 = {(short)hz,(short)one,(short)one,(short)gnh,(short)gnl,0,0,0};
    *(bf16x8*)p0 = h0;
    *(bf16x8*)p1 = h1;
}

__global__ __launch_bounds__(BLOCK, 4) void chamfer_partial(
    const float* __restrict__ pred, const float* __restrict__ gt,
    const bf16x8* __restrict__ bpack, float* __restrict__ out)
{
    __shared__ float cbuf[PPW * 16 * 128];  // 16 KB combine buffer (epilogue only)
    __shared__ float wsum[2];
    const int dirb = blockIdx.x;            // low grid bits -> XCD = dirb%8
    const int dir  = dirb >> 3, b = dirb & 7;
    const int w    = threadIdx.x >> 6, lane = threadIdx.x & 63;
    const int halfk = lane >> 5,  col = lane & 31;
    const int nsub = w & 1;                 // which n-tile pair
    const int mh   = w >> 1;                // m-half: 0 -> tiles 0..127, 1 -> 128..255

    const float* src  = dir ? gt : pred;
    const float* srcb = src + (size_t)b * N_DIM * 3;

    // A fragments for this wave's PPW n-tiles (row = col, k-half = halfk).
    bf16x8 afrag[PPW];
    #pragma unroll
    for (int p = 0; p < PPW; ++p) {
        const int ntile = blockIdx.y * 4 + nsub * 2 + p;
        const int n = ntile * 32 + col;
        const float x = srcb[3*n+0], y = srcb[3*n+1], z = srcb[3*n+2];
        const float ax = -2.f*x, ay = -2.f*y, az = -2.f*z;
        const unsigned short ahx = bf16_rne(ax), ahy = bf16_rne(ay), ahz = bf16_rne(az);
        const unsigned short alx = bf16_rne(ax - bf16f(ahx));
        const unsigned short aly = bf16_rne(ay - bf16f(ahy));
        const unsigned short alz = bf16_rne(az - bf16f(ahz));
        const float pn = x*x + y*y + z*z;
        const unsigned short pnh = bf16_rne(pn), pnl = bf16_rne(pn - bf16f(pnh));
        const unsigned short one = 0x3F80;
        bf16x8 a0 = {(short)ahx,(short)ahy,(short)ahz,(short)ahx,(short)ahy,(short)ahz,(short)alx,(short)aly};
        bf16x8 a1 = {(short)alz,(short)pnh,(short)pnl,(short)one,(short)one,0,0,0};
        afrag[p] = (halfk == 0) ? a0 : a1;
    }

    float best[PPW][16];
    #pragma unroll
    for (int p = 0; p < PPW; ++p)
        #pragma unroll
        for (int r = 0; r < 16; ++r) best[p][r] = 1e30f;

    // This wave's B-fragment stream: 128 m-tiles, 1 KB (wave) per tile,
    // coalesced dwordx4 per lane, L2-resident.
    const bf16x8* bw = bpack + (size_t)dirb * (MT * 64) + (size_t)(mh * 128) * 64 + lane;

    for (int t = 0; t < 64; ++t) {
        const bf16x8 c0 = bw[0];     // m-tile 2t
        const bf16x8 c1 = bw[64];    // m-tile 2t+1
        bw += 128;
        // group p=0: two MFMAs, C = inline 0 (no czero regs), d forced to
        // arch VGPRs by "=&v"; in-asm s_nop 7+3 covers the MFMA->VALU
        // read hazard (R10-proven-correct pattern).
        f32x16 d0, d1;
        asm volatile(
            "v_mfma_f32_32x32x16_bf16 %0, %2, %3, 0\n\t"
            "v_mfma_f32_32x32x16_bf16 %1, %2, %4, 0\n\t"
            "s_nop 7\n\t"
            "s_nop 3"
            : "=&v"(d0), "=&v"(d1)
            : "v"(afrag[0]), "v"(c0), "v"(c1));
        __builtin_amdgcn_sched_barrier(0x34);   // VALU may not cross; VMEM/SALU may
        #pragma unroll
        for (int r = 0; r < 16; ++r)
            best[0][r] = fminf(fminf(best[0][r], d0[r]), d1[r]);  // v_min3_f32
        // group p=1
        f32x16 d2, d3;
        asm volatile(
            "v_mfma_f32_32x32x16_bf16 %0, %2, %3, 0\n\t"
            "v_mfma_f32_32x32x16_bf16 %1, %2, %4, 0\n\t"
            "s_nop 7\n\t"
            "s_nop 3"
            : "=&v"(d2), "=&v"(d3)
            : "v"(afrag[1]), "v"(c0), "v"(c1));
        __builtin_amdgcn_sched_barrier(0x34);
        #pragma unroll
        for (int r = 0; r < 16; ++r)
            best[1][r] = fminf(fminf(best[1][r], d2[r]), d3[r]);
    }

    // Combine the two m-halves: waves 2,3 export best[] through LDS,
    // waves 0,1 min-combine. Lanes contiguous -> conflict-free.
    if (mh == 1) {
        #pragma unroll
        for (int p = 0; p < PPW; ++p)
            #pragma unroll
            for (int r = 0; r < 16; ++r)
                cbuf[(p * 16 + r) * 128 + nsub * 64 + lane] = best[p][r];
    }
    __syncthreads();
    if (mh == 0) {
        float bsum = 0.f;
        #pragma unroll
        for (int p = 0; p < PPW; ++p) {
            float s = 0.f;
            #pragma unroll
            for (int r = 0; r < 16; ++r) {
                float v = fminf(best[p][r], cbuf[(p * 16 + r) * 128 + nsub * 64 + lane]);
                v = fminf(v, __shfl_xor(v, 1,  64));
                v = fminf(v, __shfl_xor(v, 2,  64));
                v = fminf(v, __shfl_xor(v, 4,  64));
                v = fminf(v, __shfl_xor(v, 8,  64));
                v = fminf(v, __shfl_xor(v, 16, 64));
                s += v;                       // 16 final row-mins of this k-half
            }
            bsum += s + __shfl_xor(s, 32, 64);  // add other k-half's 16 rows
        }
        if (lane == 0) wsum[nsub] = bsum;
    }
    __syncthreads();
    if (threadIdx.x == 0) {
        const float scale = 100.0f * 0.5f / ((float)B_DIM * (float)N_DIM);
        atomicAdd(out, (wsum[0] + wsum[1]) * scale);
    }
}

extern "C" void kernel_launch(void* const* d_in, const int* in_sizes, int n_in,
                              void* d_out, int out_size, void* d_ws, size_t ws_size,
                              hipStream_t stream) {
    const float* pred = (const float*)d_in[0];
    const float* gt   = (const float*)d_in[1];
    float* out = (float*)d_out;
    unsigned short* bpack = (unsigned short*)d_ws;   // 4 MiB

    chamfer_prep<<<(2 * B_DIM * N_DIM) / 256, 256, 0, stream>>>(pred, gt, bpack, out);

    // dirb x n-chunks(128 pts) = 16 x 64 = 1024 blocks, 4 indep waves each
    dim3 grid(16, N_DIM / 128);
    chamfer_partial<<<grid, BLOCK, 0, stream>>>(pred, gt, (const bf16x8*)bpack, out);
}